// Round 1
// baseline (7271.301 us; speedup 1.0000x reference)
//
#include <hip/hip_runtime.h>
#include <math.h>

#define Sx 128
#define Bx 1024
#define D0x 300
#define D1x 74
#define D2x 35
#define HIDx 40
#define EMBx 256
#define Mx 3
#define KXx 115            // reduced width = 40+40+35
#define KTOTx 371          // 115 + 256
#define KPADx 384
#define TAUx 5.0f

// ---------------- prep: fold prev-feedback into W_hh, pack transposed weights ----------------
// Wt3[k][d][q] (k<384, d<256, q<4), col j = q*256+d :
//   k<115   -> W_ih[j][k]
//   115..370-> W_hh[j][k-115] + sum_p W_ih[j][115+p] * W_dec[p][k-115]
//   else 0
// WTA[k][tx][q] (k<304): col c=q*16+tx : (c<40 && k<300) ? W0[c][k] : 0
// WTB[k][tx][q] (k<76):  (c<40 && k<74) ? W1[c][k] : 0
// bias0[j] = b_ih+b_hh ; bias2[j] = bias0 + sum_p W_ih[j][115+p]*b_dec[p]
__global__ __launch_bounds__(256) void k_prep(
    const float* __restrict__ W0, const float* __restrict__ W1,
    const float* __restrict__ W_ih, const float* __restrict__ W_hh,
    const float* __restrict__ W_dec, const float* __restrict__ b_ih,
    const float* __restrict__ b_hh, const float* __restrict__ b_dec,
    float* __restrict__ Wt3, float* __restrict__ WTA, float* __restrict__ WTB,
    float* __restrict__ bias0, float* __restrict__ bias2) {
  int idx = blockIdx.x * 256 + threadIdx.x;
  if (idx < KPADx * 1024) {
    int k = idx >> 10, rem = idx & 1023;
    int dd = rem >> 2, q = rem & 3;
    int j = q * 256 + dd;
    float v = 0.f;
    if (k < KXx) {
      v = W_ih[j * 121 + k];
    } else if (k < KTOTx) {
      int kh = k - KXx;
      v = W_hh[j * 256 + kh];
#pragma unroll
      for (int p = 0; p < 6; ++p)
        v = fmaf(W_ih[j * 121 + 115 + p], W_dec[p * 256 + kh], v);
    }
    Wt3[idx] = v;
    return;
  }
  int r1 = idx - KPADx * 1024;
  if (r1 < 304 * 64) {
    int k = r1 >> 6, rem = r1 & 63;
    int txx = rem >> 2, q = rem & 3, c = q * 16 + txx;
    WTA[r1] = (c < 40 && k < 300) ? W0[c * 300 + k] : 0.f;
    return;
  }
  int r2 = r1 - 304 * 64;
  if (r2 < 76 * 64) {
    int k = r2 >> 6, rem = r2 & 63;
    int txx = rem >> 2, q = rem & 3, c = q * 16 + txx;
    WTB[r2] = (c < 40 && k < 74) ? W1[c * 74 + k] : 0.f;
    return;
  }
  int r3 = r2 - 76 * 64;
  if (r3 < 1024) {
    int j = r3;
    float b = b_ih[j] + b_hh[j];
    bias0[j] = b;
    float b2 = b;
#pragma unroll
    for (int p = 0; p < 6; ++p) b2 = fmaf(W_ih[j * 121 + 115 + p], b_dec[p], b2);
    bias2[j] = b2;
  }
}

// ---------------- copy x2 into reduced[:, 80:115] ----------------
__global__ __launch_bounds__(256) void k_copy_x2(const float* __restrict__ x2,
                                                 float* __restrict__ reduced) {
  int id = blockIdx.x * 256 + threadIdx.x;
  if (id >= Sx * Bx * D2x) return;
  int row = id / 35, jj = id - row * 35;
  reduced[(size_t)row * KXx + 80 + jj] = x2[id];
}

// ---------------- generic tiled GEMM (+LSTM epilogue for MODE 2) ----------------
// MODE 0: reduced[:, 0:40]  = x0 @ W0^T + b0   (K=300, 64 padded cols)
// MODE 1: reduced[:, 40:80] = x1 @ W1^T + b1   (K=74)
// MODE 2: one LSTM step: gates = reduced_t @ Wr^T + h @ W_hh'^T + bias ; c,h update
// block: 64 rows x 64 cols, 512 threads, thread = (tx 16, ty 32), acc[2][4]
template <int MODE, int KB, int CSZ>
__device__ __forceinline__ void gemm_chunk(const float* __restrict__ Xa,
                                           const float* __restrict__ Xb,
                                           const float* __restrict__ WT,
                                           int r0, int d, int tid, int ty,
                                           float (&acc)[2][4], float (*xs)[196]) {
  constexpr int DCOLS = (MODE == 2) ? 256 : 16;
  constexpr int KD = (MODE == 0) ? 300 : ((MODE == 1) ? 74 : 0);
  constexpr int LDX = (MODE == 0) ? 300 : 74;
  for (int i = tid; i < 64 * CSZ; i += 512) {
    int r = i / CSZ, kk = i - r * CSZ, k = KB + kk;
    float v = 0.f;
    if constexpr (MODE == 2) {
      if (k < KXx) v = Xa[(size_t)(r0 + r) * KXx + k];
      else if (k < KTOTx) v = Xb[(size_t)(r0 + r) * EMBx + (k - KXx)];
    } else {
      if (k < KD) v = Xa[(size_t)(r0 + r) * LDX + k];
    }
    xs[r][kk] = v;
  }
  __syncthreads();
  const float* wp = WT + ((size_t)KB * DCOLS + d) * 4;
  for (int kk = 0; kk < CSZ; kk += 4) {
    float4 w0 = *(const float4*)(wp + (size_t)(kk + 0) * DCOLS * 4);
    float4 w1 = *(const float4*)(wp + (size_t)(kk + 1) * DCOLS * 4);
    float4 w2 = *(const float4*)(wp + (size_t)(kk + 2) * DCOLS * 4);
    float4 w3 = *(const float4*)(wp + (size_t)(kk + 3) * DCOLS * 4);
#pragma unroll
    for (int rr = 0; rr < 2; ++rr) {
      float4 xv = *(const float4*)(&xs[ty * 2 + rr][kk]);
      acc[rr][0] = fmaf(xv.x, w0.x, acc[rr][0]);
      acc[rr][1] = fmaf(xv.x, w0.y, acc[rr][1]);
      acc[rr][2] = fmaf(xv.x, w0.z, acc[rr][2]);
      acc[rr][3] = fmaf(xv.x, w0.w, acc[rr][3]);
      acc[rr][0] = fmaf(xv.y, w1.x, acc[rr][0]);
      acc[rr][1] = fmaf(xv.y, w1.y, acc[rr][1]);
      acc[rr][2] = fmaf(xv.y, w1.z, acc[rr][2]);
      acc[rr][3] = fmaf(xv.y, w1.w, acc[rr][3]);
      acc[rr][0] = fmaf(xv.z, w2.x, acc[rr][0]);
      acc[rr][1] = fmaf(xv.z, w2.y, acc[rr][1]);
      acc[rr][2] = fmaf(xv.z, w2.z, acc[rr][2]);
      acc[rr][3] = fmaf(xv.z, w2.w, acc[rr][3]);
      acc[rr][0] = fmaf(xv.w, w3.x, acc[rr][0]);
      acc[rr][1] = fmaf(xv.w, w3.y, acc[rr][1]);
      acc[rr][2] = fmaf(xv.w, w3.z, acc[rr][2]);
      acc[rr][3] = fmaf(xv.w, w3.w, acc[rr][3]);
    }
  }
}

template <int MODE>
__global__ __launch_bounds__(512) void k_gemm(const float* __restrict__ Xa,
                                              const float* __restrict__ Xb,
                                              const float* __restrict__ WT,
                                              const float* __restrict__ bias,
                                              float* __restrict__ outp,
                                              float* __restrict__ cbuf) {
  __shared__ __align__(16) float xs[64][196];
  constexpr int CS0 = (MODE == 1) ? 76 : 192;
  constexpr int CS1 = (MODE == 0) ? 112 : ((MODE == 1) ? 0 : 180);

  int bid = blockIdx.x;
  int r0, d0;
  if constexpr (MODE == 2) { r0 = (bid >> 4) * 64; d0 = (bid & 15) * 16; }
  else { r0 = bid * 64; d0 = 0; }
  int tid = threadIdx.x;
  int tx = tid & 15, ty = tid >> 4;
  int d = d0 + tx;
  float acc[2][4] = {{0.f, 0.f, 0.f, 0.f}, {0.f, 0.f, 0.f, 0.f}};

  gemm_chunk<MODE, 0, CS0>(Xa, Xb, WT, r0, d, tid, ty, acc, xs);
  if constexpr (CS1 > 0) {
    __syncthreads();
    gemm_chunk<MODE, CS0, CS1>(Xa, Xb, WT, r0, d, tid, ty, acc, xs);
  }

  if constexpr (MODE == 2) {
#pragma unroll
    for (int rr = 0; rr < 2; ++rr) {
      int row = r0 + ty * 2 + rr;
      float iv = acc[rr][0] + bias[d];
      float fv = acc[rr][1] + bias[256 + d];
      float gv = acc[rr][2] + bias[512 + d];
      float ov = acc[rr][3] + bias[768 + d];
      float si = 1.f / (1.f + expf(-iv));
      float sf = 1.f / (1.f + expf(-fv));
      float so = 1.f / (1.f + expf(-ov));
      float tg = tanhf(gv);
      size_t ci = (size_t)row * EMBx + d;
      float cn = __fadd_rn(__fmul_rn(sf, cbuf[ci]), __fmul_rn(si, tg));
      cbuf[ci] = cn;
      outp[ci] = __fmul_rn(so, tanhf(cn));
    }
  } else {
    constexpr int OFF = (MODE == 0) ? 0 : 40;
#pragma unroll
    for (int rr = 0; rr < 2; ++rr) {
      int row = r0 + ty * 2 + rr;
#pragma unroll
      for (int q = 0; q < 4; ++q) {
        int c = q * 16 + tx;
        if (c < 40) outp[(size_t)row * KXx + OFF + c] = acc[rr][q] + bias[c];
      }
    }
  }
}

// ---------------- outputs: logits + gumbel decisions (wave per (s,b) row) ----------------
__global__ __launch_bounds__(256) void k_out(const float* __restrict__ hbase,
                                             const float* __restrict__ W_dec,
                                             const float* __restrict__ b_dec,
                                             const float* __restrict__ gu,
                                             float* __restrict__ outp,
                                             int s_start, int nrows) {
  int lane = threadIdx.x & 63;
  int row = blockIdx.x * 4 + (threadIdx.x >> 6);
  if (row >= nrows) return;
  int s = s_start + (row >> 10), b = row & 1023;
  const float* h = hbase + (size_t)row * EMBx;
  float4 hv = *(const float4*)(h + lane * 4);
  float a[6];
#pragma unroll
  for (int p = 0; p < 6; ++p) {
    float4 wv = *(const float4*)(W_dec + p * EMBx + lane * 4);
    a[p] = hv.x * wv.x + hv.y * wv.y + hv.z * wv.z + hv.w * wv.w;
  }
#pragma unroll
  for (int p = 0; p < 6; ++p) {
#pragma unroll
    for (int off = 32; off > 0; off >>= 1) a[p] += __shfl_xor(a[p], off, 64);
  }
  if (lane < 6) {
    int m = lane >> 1, o = lane & 1;
    outp[(size_t)Sx * Mx * Bx + (((size_t)(s * Mx + m) * Bx + b) << 1) + o] =
        a[lane] + b_dec[lane];
  }
  if (lane < 3) {
    int m = lane;
    float l0 = a[2 * m] + b_dec[2 * m];
    float l1 = a[2 * m + 1] + b_dec[2 * m + 1];
    const float* up = gu + (((size_t)s * 3072 + m * 1024 + b) << 1);
    float g0 = -logf(-logf(up[0]));
    float g1 = -logf(-logf(up[1]));
    float v0 = (l0 + g0) / TAUx;
    float v1 = (l1 + g1) / TAUx;
    outp[(size_t)s * Mx * Bx + m * Bx + b] = (v1 > v0) ? 1.0f : 0.0f;
  }
}

extern "C" void kernel_launch(void* const* d_in, const int* in_sizes, int n_in,
                              void* d_out, int out_size, void* d_ws, size_t ws_size,
                              hipStream_t stream) {
  const float* x0 = (const float*)d_in[0];
  const float* x1 = (const float*)d_in[1];
  const float* x2 = (const float*)d_in[2];
  // d_in[3] = x_lens (unused by reference)
  const float* gu = (const float*)d_in[4];
  const float* W0 = (const float*)d_in[5];
  const float* b0 = (const float*)d_in[6];
  const float* W1 = (const float*)d_in[7];
  const float* b1 = (const float*)d_in[8];
  const float* W_ih = (const float*)d_in[9];
  const float* W_hh = (const float*)d_in[10];
  const float* b_ih = (const float*)d_in[11];
  const float* b_hh = (const float*)d_in[12];
  const float* W_dec = (const float*)d_in[13];
  const float* b_dec = (const float*)d_in[14];
  float* outp = (float*)d_out;

  float* ws = (float*)d_ws;
  float* Wt3 = ws;                       // 384*1024        = 393216
  float* WTA = Wt3 + 393216;             // 304*64          = 19456
  float* WTB = WTA + 19456;              // 76*64           = 4864
  float* bias0 = WTB + 4864;             // 1024
  float* bias2 = bias0 + 1024;           // 1024
  float* cbuf = bias2 + 1024;            // 1024*256        = 262144
  float* reduced = cbuf + 262144;        // 128*1024*115    = 15073280
  float* hall = reduced + (size_t)15073280;

  size_t base_f = 393216 + 19456 + 4864 + 1024 + 1024 + 262144 + (size_t)15073280;
  size_t need_full = (base_f + (size_t)129 * 262144) * 4;
  bool full = ws_size >= need_full;

  hipMemsetAsync(cbuf, 0, 262144 * 4, stream);
  hipMemsetAsync(hall, 0, 262144 * 4, stream);  // h slot 0 = zeros

  k_prep<<<1635, 256, 0, stream>>>(W0, W1, W_ih, W_hh, W_dec, b_ih, b_hh, b_dec,
                                   Wt3, WTA, WTB, bias0, bias2);
  k_gemm<0><<<2048, 512, 0, stream>>>(x0, nullptr, WTA, b0, reduced, nullptr);
  k_gemm<1><<<2048, 512, 0, stream>>>(x1, nullptr, WTB, b1, reduced, nullptr);
  k_copy_x2<<<(Sx * Bx * D2x + 255) / 256, 256, 0, stream>>>(x2, reduced);

  for (int t = 0; t < Sx; ++t) {
    const float* hin;
    float* hout;
    if (full) {
      hin = hall + (size_t)t * 262144;
      hout = hall + (size_t)(t + 1) * 262144;
    } else {
      hin = hall + (size_t)(t & 1) * 262144;
      hout = hall + (size_t)((t + 1) & 1) * 262144;
    }
    k_gemm<2><<<256, 512, 0, stream>>>(reduced + (size_t)t * Bx * KXx, hin, Wt3,
                                       (t == 0) ? bias0 : bias2, hout, cbuf);
    if (!full) {
      k_out<<<256, 256, 0, stream>>>(hout, W_dec, b_dec, gu, outp, t, Bx);
    }
  }
  if (full) {
    k_out<<<(Sx * Bx) / 4, 256, 0, stream>>>(hall + 262144, W_dec, b_dec, gu,
                                             outp, 0, Sx * Bx);
  }
}